// Round 5
// baseline (257.660 us; speedup 1.0000x reference)
//
#include <hip/hip_runtime.h>
#include <stdint.h>

#define BATCH 256
#define QN 64
#define HN 2048
#define H2 (HN / 2)        // 1024
#define RPS 4              // rows per stage == waves per block
#define STAGES 8           // stages per block
#define RPB (RPS * STAGES) // 32 rows per block -> 512 blocks = 2/CU

typedef float v4f __attribute__((ext_vector_type(4)));
typedef float v2f __attribute__((ext_vector_type(2)));

typedef __attribute__((address_space(3))) uint32_t lds_u32;
typedef __attribute__((address_space(1))) const uint32_t glb_u32;

// Kernel A: factor[k][h] = prod_{j>k} W[k][j][h] * prod_{i<k} W[i][k][h]
__global__ __launch_bounds__(256) void factor_kernel(const float* __restrict__ W,
                                                     float* __restrict__ factor) {
    int idx = blockIdx.x * blockDim.x + threadIdx.x;
    int h2 = idx & (H2 - 1);
    int k  = idx >> 10;
    const v2f* W2 = (const v2f*)W;
    v2f p = {1.f, 1.f};
    #pragma unroll 8
    for (int j = k + 1; j < QN; ++j)
        p *= __builtin_nontemporal_load(&W2[(size_t)(k * QN + j) * H2 + h2]);
    #pragma unroll 8
    for (int i = 0; i < k; ++i)
        p *= __builtin_nontemporal_load(&W2[(size_t)(i * QN + k) * H2 + h2]);
    ((v2f*)factor)[(size_t)k * H2 + h2] = p;   // normal store -> stays in L2
}

// Kernel B: async-staged streaming normalize.
// Block = 4 waves; each wave owns 1 row (8 KB) per stage; 8 stages; LDS
// double buffer 2x32KB = 64 KB. Pending HBM bytes live in LDS, not VGPRs:
// each block keeps ~32 KB in flight across the barrier -> HBM-saturated.
__global__ __launch_bounds__(256, 2) void normalize_kernel(const float* __restrict__ x,
                                                           const float* __restrict__ factor,
                                                           float* __restrict__ out) {
    __shared__ float xs[2][RPS][HN];    // 64 KB
    const int t    = threadIdx.x;
    const int wave = t >> 6;
    const int lane = t & 63;
    const size_t row0 = (size_t)blockIdx.x * RPB;

    // issue one stage: each wave streams its row into LDS via global_load_lds
    // (dst is wave-uniform base; HW scatters lane i at base + i*16)
    auto issue = [&](int s, int buf) {
        const float* src = x + (row0 + (size_t)s * RPS + wave) * HN + lane * 4;
        float* dst = &xs[buf][wave][0];
        #pragma unroll
        for (int i = 0; i < 8; ++i)
            __builtin_amdgcn_global_load_lds((glb_u32*)(src + i * 256),
                                             (lds_u32*)(dst + i * 256), 16, 0, 0);
    };

    issue(0, 0);

    for (int s = 0; s < STAGES; ++s) {
        const int buf = s & 1;
        const size_t row = row0 + (size_t)s * RPS + wave;
        const int q = (int)(row & (QN - 1));

        // prefetch this row's factor into regs (L2-hit; drained at barrier)
        const v4f* f4 = (const v4f*)(factor + (size_t)q * HN);
        v4f b[8];
        #pragma unroll
        for (int i = 0; i < 8; ++i) b[i] = f4[lane + 64 * i];

        __syncthreads();                    // drains stage s x-loads (vmcnt 0)
        if (s + 1 < STAGES) issue(s + 1, buf ^ 1);

        // consume stage s from LDS
        const v4f* s4 = (const v4f*)&xs[buf][wave][0];
        v4f a[8];
        float ss = 0.f;
        #pragma unroll
        for (int i = 0; i < 8; ++i) {
            a[i] = s4[lane + 64 * i] * b[i];
            ss += a[i].x * a[i].x + a[i].y * a[i].y + a[i].z * a[i].z + a[i].w * a[i].w;
        }
        #pragma unroll
        for (int off = 32; off >= 1; off >>= 1)
            ss += __shfl_xor(ss, off, 64);
        float inv = 1.0f / fmaxf(sqrtf(ss), 1e-12f);

        v4f* o4 = (v4f*)(out + row * HN);
        #pragma unroll
        for (int i = 0; i < 8; ++i) {
            v4f yi = a[i] * inv;
            __builtin_nontemporal_store(yi, &o4[lane + 64 * i]);
        }
        // note: next iteration's __syncthreads waits for these stores too,
        // but they complete to L2 quickly relative to the 32 KB stage fill.
    }
}

extern "C" void kernel_launch(void* const* d_in, const int* in_sizes, int n_in,
                              void* d_out, int out_size, void* d_ws, size_t ws_size,
                              hipStream_t stream) {
    const float* x = (const float*)d_in[0];
    const float* W = (const float*)d_in[1];
    float* out     = (float*)d_out;
    float* factor  = (float*)d_ws;   // QN*HN floats = 512 KB

    factor_kernel<<<(QN * H2) / 256, 256, 0, stream>>>(W, factor);
    normalize_kernel<<<(BATCH * QN) / RPB, 256, 0, stream>>>(x, factor, out);
}